// Round 8
// baseline (739.186 us; speedup 1.0000x reference)
//
#include <hip/hip_runtime.h>
#include <hip/hip_bf16.h>

typedef _Float16 f16_t;
typedef _Float16 f16x4v __attribute__((ext_vector_type(4)));
typedef _Float16 f16x8 __attribute__((ext_vector_type(8)));
typedef float f32x4 __attribute__((ext_vector_type(4)));

// ================= 128x128 GEMM core: C = A[M,K] @ B^T (B stored [N][K]) =================
// 4 waves in 2x2, each wave 64x64 via 4x4 frags of 16x16x32.
template<bool BIAS, bool RELU, bool OUTF16, bool GATHER>
__device__ __forceinline__ void gemm128_body(
    const f16_t* __restrict__ A, const f16_t* __restrict__ B,
    void* __restrict__ Cv, const float* __restrict__ bias,
    const int* __restrict__ tok_of_slot,
    int m0, int n0, int K, int lda, int ldb, int ldc)
{
    __shared__ f16_t As[128][72];
    __shared__ f16_t Bs[128][72];
    const int t = threadIdx.x, wave = t >> 6, lane = t & 63;
    const int wr2 = (wave >> 1) * 64, wc2 = (wave & 1) * 64;
    const int lr = lane & 15, kg = lane >> 4;
    const int sr = t >> 1, sc0 = (t & 1) * 32;

    const f16_t* arp;
    if constexpr (GATHER) arp = A + (long long)(tok_of_slot[m0 + sr] & 8191) * lda;
    else                  arp = A + (long long)(m0 + sr) * lda;
    const f16_t* brp = B + (long long)(n0 + sr) * ldb;

    f32x4 acc[4][4] = {};
    for (int k0 = 0; k0 < K; k0 += 64) {
        #pragma unroll
        for (int j = 0; j < 4; j++) {
            *reinterpret_cast<f16x8*>(&As[sr][sc0 + j * 8]) =
                *reinterpret_cast<const f16x8*>(&arp[k0 + sc0 + j * 8]);
            *reinterpret_cast<f16x8*>(&Bs[sr][sc0 + j * 8]) =
                *reinterpret_cast<const f16x8*>(&brp[k0 + sc0 + j * 8]);
        }
        __syncthreads();
        #pragma unroll
        for (int c = 0; c < 2; c++) {
            f16x8 av[4], bv[4];
            #pragma unroll
            for (int i = 0; i < 4; i++) {
                av[i] = *reinterpret_cast<const f16x8*>(&As[wr2 + i * 16 + lr][c * 32 + kg * 8]);
                bv[i] = *reinterpret_cast<const f16x8*>(&Bs[wc2 + i * 16 + lr][c * 32 + kg * 8]);
            }
            #pragma unroll
            for (int mi = 0; mi < 4; mi++)
                #pragma unroll
                for (int ni = 0; ni < 4; ni++)
                    acc[mi][ni] = __builtin_amdgcn_mfma_f32_16x16x32_f16(av[mi], bv[ni], acc[mi][ni], 0, 0, 0);
        }
        __syncthreads();
    }
    #pragma unroll
    for (int mi = 0; mi < 4; mi++)
        #pragma unroll
        for (int ni = 0; ni < 4; ni++)
            #pragma unroll
            for (int r = 0; r < 4; r++) {
                const int row = m0 + wr2 + mi * 16 + kg * 4 + r;
                const int col = n0 + wc2 + ni * 16 + lr;
                float v = acc[mi][ni][r];
                if constexpr (BIAS) v += bias[col];
                if constexpr (RELU) v = fmaxf(v, 0.f);
                if constexpr (OUTF16) ((f16_t*)Cv)[(long long)row * ldc + col] = (f16_t)v;
                else                  ((float*)Cv)[(long long)row * ldc + col] = v;
            }
}

template<bool BIAS, bool OUTF16>
__global__ __launch_bounds__(256) void gemm128_kernel(
    const f16_t* __restrict__ A, const f16_t* __restrict__ B, void* __restrict__ Cv,
    const float* __restrict__ bias, int K, int lda, int ldb, int ldc)
{
    gemm128_body<BIAS, false, OUTF16, false>(A, B, Cv, bias, nullptr,
                                             blockIdx.y * 128, blockIdx.x * 128, K, lda, ldb, ldc);
}

// fused Q/K/V projection: z picks {A, W, bias, out}
__global__ __launch_bounds__(256) void qkv128_kernel(
    const f16_t* __restrict__ Aq, const f16_t* __restrict__ Akv,
    const f16_t* __restrict__ B0, const f16_t* __restrict__ B1, const f16_t* __restrict__ B2,
    const float* __restrict__ bi0, const float* __restrict__ bi1, const float* __restrict__ bi2,
    f16_t* __restrict__ C0, f16_t* __restrict__ C1, f16_t* __restrict__ C2)
{
    const int zz = blockIdx.z;
    const f16_t* A = (zz == 0) ? Aq : Akv;
    const f16_t* B = (zz == 0) ? B0 : (zz == 1 ? B1 : B2);
    const float* bias = (zz == 0) ? bi0 : (zz == 1 ? bi1 : bi2);
    f16_t* C = (zz == 0) ? C0 : (zz == 1 ? C1 : C2);
    gemm128_body<true, false, true, false>(A, B, C, bias, nullptr,
                                           blockIdx.y * 128, blockIdx.x * 128, 256, 256, 256, 256);
}

// MoE GEMM: expert from 128-aligned block row
template<bool RELU, bool OUTF16, bool GATHER>
__global__ __launch_bounds__(256) void moe_gemm128_kernel(
    const f16_t* __restrict__ A, const int* __restrict__ tok_of_slot,
    const f16_t* __restrict__ W, const float* __restrict__ bias,
    void* __restrict__ Cv, const int* __restrict__ ebase,
    int K, int lda, int ldb, int ldc, int wstride, int bstride)
{
    const int m0 = blockIdx.y * 128;
    if (m0 >= ebase[8]) return;
    int e = 0;
    #pragma unroll
    for (int i = 1; i < 8; i++) if (m0 >= ebase[i]) e = i;
    gemm128_body<true, RELU, OUTF16, GATHER>(
        A, W + (long long)e * wstride, Cv, bias + e * bstride, tok_of_slot,
        m0, blockIdx.x * 128, K, lda, ldb, ldc);
}

// ================= V transpose: VT[z][d][s] from V16 [token][256] =================
__global__ __launch_bounds__(256) void vtrans_kernel(
    const f16_t* __restrict__ V16, f16_t* __restrict__ VT)
{
    __shared__ f16_t tile[32][33];
    const int z = blockIdx.z;
    const int s0 = blockIdx.x * 32, d0 = blockIdx.y * 32;
    const int tx = threadIdx.x & 31, ty = threadIdx.x >> 5;
    #pragma unroll
    for (int i = 0; i < 32; i += 8)
        tile[ty + i][tx] = V16[(long long)(s0 + ty + i) * 1024 + 64 * z + d0 + tx];
    __syncthreads();
    #pragma unroll
    for (int i = 0; i < 32; i += 8)
        VT[(long long)z * 131072 + (long long)(d0 + ty + i) * 2048 + s0 + tx] = tile[tx][ty + i];
}

// ================= flash attention, split-KV; barrier-free, K/V direct from L2 =========
// chunk c covers k in [c*512, (c+1)*512). Writes unnormalized Opart (f16) + per-row m,l.
__global__ __launch_bounds__(256, 6) void flash_kernel(
    const f16_t* __restrict__ Q16, const f16_t* __restrict__ K16,
    const f16_t* __restrict__ VT, f16_t* __restrict__ Opart,
    float* __restrict__ mlm, float* __restrict__ mll)
{
    __shared__ f16_t Ps[4][16][72];    // per-wave P redistribution only

    const int z = blockIdx.y;
    const int c = blockIdx.z;
    const int m0 = blockIdx.x * 64;
    const int t = threadIdx.x, w = t >> 6, lane = t & 63;
    const int lr = lane & 15, kg = lane >> 4;
    const long long cbase = 64LL * z;

    // Q fragments, pre-scaled by 1/8 (exact pow2)
    f16x8 qf0, qf1;
    {
        const long long qrow = (long long)(m0 + w * 16 + lr) * 1024 + cbase;
        qf0 = *reinterpret_cast<const f16x8*>(&Q16[qrow + kg * 8]);
        qf1 = *reinterpret_cast<const f16x8*>(&Q16[qrow + 32 + kg * 8]);
        #pragma unroll
        for (int i = 0; i < 8; i++) { qf0[i] *= (f16_t)0.125f; qf1[i] *= (f16_t)0.125f; }
    }

    // per-lane operand base pointers (L2-resident slices)
    const f16_t* kp = K16 + cbase + (long long)lr * 1024 + kg * 8;          // + (n0+nt*16)*1024 [+32]
    const f16_t* vp = VT + (long long)z * 131072 + (long long)lr * 2048 + kg * 8; // + dt*16*2048 + n0 [+32]

    f32x4 oacc[4] = {};
    float mrun[4] = { -1e30f, -1e30f, -1e30f, -1e30f };
    float lrun[4] = {};

    const int nbeg = c * 512, nend = nbeg + 512;
    for (int n0 = nbeg; n0 < nend; n0 += 64) {
        // ---- S = (Q/8) K^T, K operands straight from global (L2) ----
        float sv[4][4];
        #pragma unroll
        for (int nt = 0; nt < 4; nt++) {
            const long long ko = (long long)(n0 + nt * 16) * 1024;
            f16x8 b0 = *reinterpret_cast<const f16x8*>(kp + ko);
            f16x8 b1 = *reinterpret_cast<const f16x8*>(kp + ko + 32);
            f32x4 acc = {};
            acc = __builtin_amdgcn_mfma_f32_16x16x32_f16(qf0, b0, acc, 0, 0, 0);
            acc = __builtin_amdgcn_mfma_f32_16x16x32_f16(qf1, b1, acc, 0, 0, 0);
            #pragma unroll
            for (int r = 0; r < 4; r++) sv[nt][r] = acc[r];
        }

        // ---- online softmax (row = kg*4+r; reduce across 16-lane group) ----
        float mnew[4], alpha[4];
        #pragma unroll
        for (int r = 0; r < 4; r++) {
            float rm = fmaxf(fmaxf(sv[0][r], sv[1][r]), fmaxf(sv[2][r], sv[3][r]));
            rm = fmaxf(rm, __shfl_xor(rm, 1));
            rm = fmaxf(rm, __shfl_xor(rm, 2));
            rm = fmaxf(rm, __shfl_xor(rm, 4));
            rm = fmaxf(rm, __shfl_xor(rm, 8));
            mnew[r] = fmaxf(mrun[r], rm);
            alpha[r] = __expf(mrun[r] - mnew[r]);
            mrun[r] = mnew[r];
        }
        #pragma unroll
        for (int nt = 0; nt < 4; nt++)
            #pragma unroll
            for (int r = 0; r < 4; r++) sv[nt][r] = __expf(sv[nt][r] - mnew[r]);
        #pragma unroll
        for (int r = 0; r < 4; r++) {
            float rs = sv[0][r] + sv[1][r] + sv[2][r] + sv[3][r];
            rs += __shfl_xor(rs, 1);
            rs += __shfl_xor(rs, 2);
            rs += __shfl_xor(rs, 4);
            rs += __shfl_xor(rs, 8);
            lrun[r] = lrun[r] * alpha[r] + rs;
        }
        #pragma unroll
        for (int dt = 0; dt < 4; dt++)
            #pragma unroll
            for (int r = 0; r < 4; r++) oacc[dt][r] *= alpha[r];

        // ---- P: C-layout -> A-layout via per-wave LDS (same-wave, no barrier) ----
        #pragma unroll
        for (int nt = 0; nt < 4; nt++)
            #pragma unroll
            for (int r = 0; r < 4; r++)
                Ps[w][kg * 4 + r][nt * 16 + lr] = (f16_t)sv[nt][r];

        f16x8 pa0 = *reinterpret_cast<const f16x8*>(&Ps[w][lr][kg * 8]);
        f16x8 pa1 = *reinterpret_cast<const f16x8*>(&Ps[w][lr][32 + kg * 8]);

        // ---- PV, V^T operands straight from global (L2) ----
        #pragma unroll
        for (int dt = 0; dt < 4; dt++) {
            const long long vo = (long long)(dt * 16) * 2048 + n0;
            f16x8 vb0 = *reinterpret_cast<const f16x8*>(vp + vo);
            f16x8 vb1 = *reinterpret_cast<const f16x8*>(vp + vo + 32);
            oacc[dt] = __builtin_amdgcn_mfma_f32_16x16x32_f16(pa0, vb0, oacc[dt], 0, 0, 0);
            oacc[dt] = __builtin_amdgcn_mfma_f32_16x16x32_f16(pa1, vb1, oacc[dt], 0, 0, 0);
        }
    }

    // ---- write unnormalized partials (f16) + (m,l) ----
    f16_t* op = Opart + (long long)c * 2097152;
    const long long orow0 = (long long)(m0 + w * 16) * 1024 + cbase;
    #pragma unroll
    for (int r = 0; r < 4; r++)
        #pragma unroll
        for (int dt = 0; dt < 4; dt++)
            op[orow0 + (long long)(kg * 4 + r) * 1024 + dt * 16 + lr] = (f16_t)oacc[dt][r];
    if (lr == 0) {
        const int b = z >> 2, h = z & 3;
        #pragma unroll
        for (int r = 0; r < 4; r++) {
            const int tok = (m0 + w * 16 + kg * 4 + r) * 4 + b;
            const long long idx = (long long)(c * 4 + h) * 8192 + tok;
            mlm[idx] = mrun[r];
            mll[idx] = lrun[r];
        }
    }
}

// ================= merge 4 split-KV chunks -> O16 f16 =================
__global__ __launch_bounds__(256) void merge_kernel(
    const f16_t* __restrict__ Opart, const float* __restrict__ mlm,
    const float* __restrict__ mll, f16_t* __restrict__ O16)
{
    const int w = threadIdx.x >> 6, lane = threadIdx.x & 63;
    const int trow = blockIdx.x * 4 + w;
    const int h = lane >> 4;
    float m[4], l[4];
    #pragma unroll
    for (int c = 0; c < 4; c++) {
        m[c] = mlm[(long long)(c * 4 + h) * 8192 + trow];
        l[c] = mll[(long long)(c * 4 + h) * 8192 + trow];
    }
    float M = fmaxf(fmaxf(m[0], m[1]), fmaxf(m[2], m[3]));
    float wv[4], L = 0.f;
    #pragma unroll
    for (int c = 0; c < 4; c++) { wv[c] = __expf(m[c] - M); L += wv[c] * l[c]; }
    const float inv = 1.f / L;
    const long long base = (long long)trow * 256 + lane * 4;
    float acc[4] = {};
    #pragma unroll
    for (int c = 0; c < 4; c++) {
        f16x4v v = *reinterpret_cast<const f16x4v*>(&Opart[(long long)c * 2097152 + base]);
        #pragma unroll
        for (int j = 0; j < 4; j++) acc[j] += wv[c] * (float)v[j];
    }
    f16_t o[4] = { (f16_t)(acc[0] * inv), (f16_t)(acc[1] * inv),
                   (f16_t)(acc[2] * inv), (f16_t)(acc[3] * inv) };
    *reinterpret_cast<ulong1*>(&O16[base]) = *reinterpret_cast<ulong1*>(o);
}

// ================= prep kernels =================
__global__ __launch_bounds__(256) void wtrans_kernel(
    const float* __restrict__ in, f16_t* __restrict__ out, int R, int C)
{
    __shared__ float tile[32][33];
    const long long zoff = (long long)blockIdx.z * R * C;
    const int r0 = blockIdx.y * 32, c0 = blockIdx.x * 32;
    const int tx = threadIdx.x & 31, ty = threadIdx.x >> 5;
    #pragma unroll
    for (int i = 0; i < 32; i += 8)
        tile[ty + i][tx] = in[zoff + (long long)(r0 + ty + i) * C + c0 + tx];
    __syncthreads();
    #pragma unroll
    for (int i = 0; i < 32; i += 8)
        out[zoff + (long long)(c0 + ty + i) * R + r0 + tx] = (f16_t)tile[tx][ty + i];
}

__global__ __launch_bounds__(256) void wtrans4_kernel(
    const float* __restrict__ W0, const float* __restrict__ W1,
    const float* __restrict__ W2, const float* __restrict__ W3,
    f16_t* __restrict__ T0, f16_t* __restrict__ T1,
    f16_t* __restrict__ T2, f16_t* __restrict__ T3)
{
    __shared__ float tile[32][33];
    const int z = blockIdx.z;
    const float* in = (z == 0) ? W0 : (z == 1 ? W1 : (z == 2 ? W2 : W3));
    f16_t* out = (z == 0) ? T0 : (z == 1 ? T1 : (z == 2 ? T2 : T3));
    const int r0 = blockIdx.y * 32, c0 = blockIdx.x * 32;
    const int tx = threadIdx.x & 31, ty = threadIdx.x >> 5;
    #pragma unroll
    for (int i = 0; i < 32; i += 8)
        tile[ty + i][tx] = in[(long long)(r0 + ty + i) * 256 + c0 + tx];
    __syncthreads();
    #pragma unroll
    for (int i = 0; i < 32; i += 8)
        out[(long long)(c0 + ty + i) * 256 + r0 + tx] = (f16_t)tile[tx][ty + i];
}

__global__ __launch_bounds__(256) void cvt16_kernel(
    const float* __restrict__ a, const float* __restrict__ b,
    f16_t* __restrict__ oa, f16_t* __restrict__ ob)
{
    long long i = ((long long)blockIdx.x * 256 + threadIdx.x) * 4;
    const float* in = a; f16_t* out = oa;
    if (i >= 2097152) { in = b; out = ob; i -= 2097152; }
    float4 v = *reinterpret_cast<const float4*>(&in[i]);
    f16_t o[4] = { (f16_t)v.x, (f16_t)v.y, (f16_t)v.z, (f16_t)v.w };
    *reinterpret_cast<ulong1*>(&out[i]) = *reinterpret_cast<ulong1*>(o);
}

// ================= LN(in1+in2)*g+b -> f32 (+optional f16) =================
__global__ __launch_bounds__(256) void ln_kernel(
    const float* __restrict__ in1, const float* __restrict__ in2,
    const float* __restrict__ gamma, const float* __restrict__ beta,
    float* __restrict__ out, f16_t* __restrict__ out16)
{
    const int wave = threadIdx.x >> 6, lane = threadIdx.x & 63;
    const long long row = (long long)blockIdx.x * 4 + wave;
    const long long base = row * 256 + lane * 4;
    float4 a = *reinterpret_cast<const float4*>(&in1[base]);
    float4 b = *reinterpret_cast<const float4*>(&in2[base]);
    float x[4] = { a.x + b.x, a.y + b.y, a.z + b.z, a.w + b.w };
    float s = x[0] + x[1] + x[2] + x[3];
    float s2 = x[0]*x[0] + x[1]*x[1] + x[2]*x[2] + x[3]*x[3];
    #pragma unroll
    for (int o = 32; o; o >>= 1) { s += __shfl_xor(s, o); s2 += __shfl_xor(s2, o); }
    const float mean = s * (1.f / 256.f);
    const float var = s2 * (1.f / 256.f) - mean * mean;
    const float rstd = rsqrtf(var + 1e-5f);
    float4 g = *reinterpret_cast<const float4*>(&gamma[lane * 4]);
    float4 bb = *reinterpret_cast<const float4*>(&beta[lane * 4]);
    const float* gf = reinterpret_cast<const float*>(&g);
    const float* bf = reinterpret_cast<const float*>(&bb);
    float y[4];
    #pragma unroll
    for (int i = 0; i < 4; i++) y[i] = (x[i] - mean) * rstd * gf[i] + bf[i];
    *reinterpret_cast<float4*>(&out[base]) = make_float4(y[0], y[1], y[2], y[3]);
    if (out16) {
        f16_t o[4] = { (f16_t)y[0], (f16_t)y[1], (f16_t)y[2], (f16_t)y[3] };
        *reinterpret_cast<ulong1*>(&out16[base]) = *reinterpret_cast<ulong1*>(o);
    }
}

// ================= gating (1 thread/token, hierarchical) =================
__global__ __launch_bounds__(256) void gating_kernel(
    const float* __restrict__ X, const float* __restrict__ Wg, const float* __restrict__ bg,
    int* __restrict__ gcount, float* __restrict__ counts,
    int* __restrict__ pos_of_tok, int* __restrict__ exp_of_tok,
    float* __restrict__ gate_of_tok)
{
    __shared__ float WgL[2048];
    __shared__ float cpart[8];
    __shared__ int lcnt[8];
    __shared__ int lbase[8];
    const int t = threadIdx.x;
    for (int i = t; i < 2048; i += 256) WgL[i] = Wg[i];
    if (t < 8) { cpart[t] = 0.f; lcnt[t] = 0; }
    __syncthreads();

    const int tok = blockIdx.x * 256 + t;
    const float* xr = X + (long long)tok * 256;
    float acc[8] = {};
    for (int k = 0; k < 256; k += 4) {
        float4 xv = *reinterpret_cast<const float4*>(xr + k);
        const float* xf = reinterpret_cast<const float*>(&xv);
        #pragma unroll
        for (int i = 0; i < 4; i++) {
            const float xi = xf[i];
            const float* wrow = &WgL[(k + i) * 8];
            #pragma unroll
            for (int e = 0; e < 8; e++) acc[e] += xi * wrow[e];
        }
    }
    float p[8]; float mx = -1e30f;
    #pragma unroll
    for (int e = 0; e < 8; e++) { p[e] = acc[e] + bg[e]; mx = fmaxf(mx, p[e]); }
    float se = 0.f;
    #pragma unroll
    for (int e = 0; e < 8; e++) { p[e] = __expf(p[e] - mx); se += p[e]; }
    const float inv = 1.f / se;
    #pragma unroll
    for (int e = 0; e < 8; e++) { p[e] *= inv; atomicAdd(&cpart[e], p[e]); }

    int i1 = 0;
    #pragma unroll
    for (int e = 1; e < 8; e++) if (p[e] > p[i1]) i1 = e;
    int i2 = (i1 == 0) ? 1 : 0;
    #pragma unroll
    for (int e = 0; e < 8; e++) if (e != i1 && p[e] > p[i2]) i2 = e;
    const float gs = 1.f / (p[i1] + p[i2]);

    const int p1 = atomicAdd(&lcnt[i1], 1);
    const int p2 = atomicAdd(&lcnt[i2], 1);
    __syncthreads();
    if (t < 8) {
        lbase[t] = atomicAdd(&gcount[t], lcnt[t]);
        atomicAdd(&counts[t], cpart[t]);
    }
    __syncthreads();
    pos_of_tok[2 * tok]     = lbase[i1] + p1;
    pos_of_tok[2 * tok + 1] = lbase[i2] + p2;
    exp_of_tok[2 * tok]     = i1;
    exp_of_tok[2 * tok + 1] = i2;
    gate_of_tok[2 * tok]     = p[i1] * gs;
    gate_of_tok[2 * tok + 1] = p[i2] * gs;
}

// 128-aligned prefix bases (tiles never span experts)
__global__ void finalize_kernel(const int* __restrict__ gcount, int* __restrict__ ebase)
{
    if (threadIdx.x == 0) {
        int b = 0;
        for (int e = 0; e < 8; e++) { ebase[e] = b; b += (gcount[e] + 127) & ~127; }
        ebase[8] = b;
    }
}

__global__ __launch_bounds__(256) void scatter_kernel(
    const int* __restrict__ pos_of_tok, const int* __restrict__ exp_of_tok,
    const int* __restrict__ ebase, int* __restrict__ tok_of_slot)
{
    const int i = blockIdx.x * 256 + threadIdx.x;
    const int e = exp_of_tok[i];
    tok_of_slot[ebase[e] + pos_of_tok[i]] = i >> 1;
}

// out = LN(gv1*Ys[s1] + gv2*Ys[s2] + X1), Ys f16
__global__ __launch_bounds__(256) void moe_combine_ln_kernel(
    const f16_t* __restrict__ Ys, const float* __restrict__ X1,
    const int* __restrict__ pos_of_tok, const int* __restrict__ exp_of_tok,
    const float* __restrict__ gate_of_tok, const int* __restrict__ ebase,
    const float* __restrict__ gamma, const float* __restrict__ beta,
    float* __restrict__ out, f16_t* __restrict__ out16)
{
    const int wave = threadIdx.x >> 6, lane = threadIdx.x & 63;
    const long long tok = (long long)blockIdx.x * 4 + wave;
    const int e1 = exp_of_tok[2 * tok], e2 = exp_of_tok[2 * tok + 1];
    const long long s1 = ebase[e1] + pos_of_tok[2 * tok];
    const long long s2 = ebase[e2] + pos_of_tok[2 * tok + 1];
    const float gv1 = gate_of_tok[2 * tok], gv2 = gate_of_tok[2 * tok + 1];
    const long long base = tok * 256 + lane * 4;
    f16x4v y1 = *reinterpret_cast<const f16x4v*>(&Ys[s1 * 256 + lane * 4]);
    f16x4v y2 = *reinterpret_cast<const f16x4v*>(&Ys[s2 * 256 + lane * 4]);
    float4 xv = *reinterpret_cast<const float4*>(&X1[base]);
    const float* xf = reinterpret_cast<const float*>(&xv);
    float x[4];
    #pragma unroll
    for (int i = 0; i < 4; i++) x[i] = gv1 * (float)y1[i] + gv2 * (float)y2[i] + xf[i];
    float s = x[0] + x[1] + x[2] + x[3];
    float s2v = x[0]*x[0] + x[1]*x[1] + x[2]*x[2] + x[3]*x[3];
    #pragma unroll
    for (int o = 32; o; o >>= 1) { s += __shfl_xor(s, o); s2v += __shfl_xor(s2v, o); }
    const float mean = s * (1.f / 256.f);
    const float var = s2v * (1.f / 256.f) - mean * mean;
    const float rstd = rsqrtf(var + 1e-5f);
    float4 g = *reinterpret_cast<const float4*>(&gamma[lane * 4]);
    float4 bb = *reinterpret_cast<const float4*>(&beta[lane * 4]);
    const float* gf = reinterpret_cast<const float*>(&g);
    const float* bf = reinterpret_cast<const float*>(&bb);
    float y[4];
    #pragma unroll
    for (int i = 0; i < 4; i++) y[i] = (x[i] - mean) * rstd * gf[i] + bf[i];
    *reinterpret_cast<float4*>(&out[base]) = make_float4(y[0], y[1], y[2], y[3]);
    if (out16) {
        f16_t o[4] = { (f16_t)y[0], (f16_t)y[1], (f16_t)y[2], (f16_t)y[3] };
        *reinterpret_cast<ulong1*>(&out16[base]) = *reinterpret_cast<ulong1*>(o);
    }
}

__global__ void aux_kernel(const float* __restrict__ counts, float* __restrict__ out)
{
    if (threadIdx.x == 0) {
        float aux = 0.f;
        for (int pzz = 0; pzz < 2; pzz++) {
            const float* c = counts + pzz * 8;
            float tot = 0.f;
            for (int e = 0; e < 8; e++) tot += c[e];
            float s = 0.f;
            for (int e = 0; e < 8; e++) s += (c[e] / tot) * (c[e] * (1.f / 8192.f));
            aux += 8.f * s;
        }
        out[0] = 0.01f * aux;
    }
}

extern "C" void kernel_launch(void* const* d_in, const int* in_sizes, int n_in,
                              void* d_out, int out_size, void* d_ws, size_t ws_size,
                              hipStream_t stream)
{
    const float* Xc  = (const float*)d_in[0];
    const float* Xt  = (const float*)d_in[1];
    const float* Wq  = (const float*)d_in[2];
    const float* Wk  = (const float*)d_in[3];
    const float* Wv  = (const float*)d_in[4];
    const float* bq  = (const float*)d_in[5];
    const float* bk  = (const float*)d_in[6];
    const float* bv  = (const float*)d_in[7];
    const float* Wo  = (const float*)d_in[8];
    const float* bo  = (const float*)d_in[9];
    const float* Wg  = (const float*)d_in[10];
    const float* bg  = (const float*)d_in[11];
    const float* W1  = (const float*)d_in[12];
    const float* b1  = (const float*)d_in[13];
    const float* W2  = (const float*)d_in[14];
    const float* b2  = (const float*)d_in[15];
    const float* g_c1 = (const float*)d_in[16];
    const float* b_c1 = (const float*)d_in[17];
    const float* g_c2 = (const float*)d_in[18];
    const float* b_c2 = (const float*)d_in[19];
    const float* g_t1 = (const float*)d_in[20];
    const float* b_t1 = (const float*)d_in[21];
    const float* g_t2 = (const float*)d_in[22];
    const float* b_t2 = (const float*)d_in[23];

    const long long NTOK = 2097152;          // 8192 tokens * 256
    const int SLOT_MAX = 17408;              // 136 * 128 (128-aligned expert bases)
    float* dout = (float*)d_out;             // fp32: xc | xt | aux
    float* xcout = dout;
    float* xtout = dout + NTOK;

    float* ws = (float*)d_ws;
    float* P1 = ws;
    float* X1 = P1 + NTOK;
    float* counts      = X1 + NTOK;                      // 16 f32
    int*   gcount      = (int*)(counts + 16);            // 16 i32 (adjacent: one memset)
    float* gate_of_tok = (float*)(gcount + 16);          // 16384
    float* mlm = gate_of_tok + 16384;                    // 4*4*8192
    float* mll = mlm + 131072;                           // 4*4*8192
    int* ebase       = (int*)(mll + 131072);             // 16
    int* pos_of_tok  = ebase + 16;                       // 16384
    int* exp_of_tok  = pos_of_tok + 16384;               // 16384
    int* tok_of_slot = exp_of_tok + 16384;               // SLOT_MAX
    f16_t* h16 = (f16_t*)(tok_of_slot + SLOT_MAX);
    f16_t* Xc16 = h16;
    f16_t* Xt16 = Xc16 + NTOK;
    f16_t* xc16 = Xt16 + NTOK;
    f16_t* Q16  = xc16 + NTOK;
    f16_t* K16  = Q16 + NTOK;
    f16_t* V16  = K16 + NTOK;
    f16_t* O16  = V16 + NTOK;
    f16_t* X116 = O16 + NTOK;
    f16_t* VT   = X116 + NTOK;                           // 16 z x 64 d x 2048 s
    f16_t* Hs16 = VT + NTOK;                             // SLOT_MAX x 1024 (MoE phase)
    f16_t* Ys16 = Hs16 + (long long)SLOT_MAX * 1024;     // SLOT_MAX x 256
    f16_t* WqT  = Ys16 + (long long)SLOT_MAX * 256;
    f16_t* WkT  = WqT + 65536;
    f16_t* WvT  = WkT + 65536;
    f16_t* WoT  = WvT + 65536;
    f16_t* W1T  = WoT + 65536;                           // 8 x 1024 x 256
    f16_t* W2T  = W1T + 2097152;                         // 8 x 256 x 1024
    f16_t* Opart = Hs16;                                 // alias: attention phase only (4*NTOK f16 = 16MB)

    hipMemsetAsync(counts, 0, 32 * sizeof(int), stream);   // counts(16f) + gcount(16i)

    // ---- prep ----
    cvt16_kernel<<<4096, 256, 0, stream>>>(Xc, Xt, Xc16, Xt16);
    wtrans4_kernel<<<dim3(8, 8, 4), 256, 0, stream>>>(Wq, Wk, Wv, Wo, WqT, WkT, WvT, WoT);
    wtrans_kernel<<<dim3(32, 8, 8), 256, 0, stream>>>(W1, W1T, 256, 1024);
    wtrans_kernel<<<dim3(8, 32, 8), 256, 0, stream>>>(W2, W2T, 1024, 256);

    for (int pass = 0; pass < 2; pass++) {
        const float*  xq    = pass ? Xt   : Xc;
        const f16_t*  xq16  = pass ? Xt16 : Xc16;
        const f16_t*  xkv16 = pass ? xc16 : Xc16;
        const float* g1  = pass ? g_t1 : g_c1;
        const float* be1 = pass ? b_t1 : b_c1;
        const float* g2  = pass ? g_t2 : g_c2;
        const float* be2 = pass ? b_t2 : b_c2;
        float* cnt = counts + pass * 8;
        int* gcnt  = gcount + pass * 8;
        float* oln = pass ? xtout : xcout;
        f16_t* oln16 = pass ? nullptr : xc16;

        // Q/K/V projections in one dispatch (128^2 tiles)
        qkv128_kernel<<<dim3(2, 64, 3), 256, 0, stream>>>(
            xq16, xkv16, WqT, WkT, WvT, bq, bk, bv, Q16, K16, V16);

        // V -> VT[z][d][s], then split-KV flash + merge
        vtrans_kernel<<<dim3(64, 2, 16), 256, 0, stream>>>(V16, VT);
        flash_kernel<<<dim3(32, 16, 4), 256, 0, stream>>>(Q16, K16, VT, Opart, mlm, mll);
        merge_kernel<<<2048, 256, 0, stream>>>(Opart, mlm, mll, O16);

        // output projection + LN1 (dual f32/f16)
        gemm128_kernel<true, false><<<dim3(2, 64), 256, 0, stream>>>(
            O16, WoT, P1, bo, 256, 256, 256, 256);
        ln_kernel<<<2048, 256, 0, stream>>>(P1, xq, g1, be1, X1, X116);

        // ---- sparse top-2 MoE ----
        gating_kernel<<<32, 256, 0, stream>>>(X1, Wg, bg, gcnt, cnt,
                                              pos_of_tok, exp_of_tok, gate_of_tok);
        finalize_kernel<<<1, 64, 0, stream>>>(gcnt, ebase);
        scatter_kernel<<<64, 256, 0, stream>>>(pos_of_tok, exp_of_tok, ebase, tok_of_slot);
        moe_gemm128_kernel<true, true, true><<<dim3(8, 136), 256, 0, stream>>>(
            X116, tok_of_slot, W1T, b1, Hs16, ebase,
            256, 256, 256, 1024, 262144, 1024);
        moe_gemm128_kernel<false, true, false><<<dim3(2, 136), 256, 0, stream>>>(
            Hs16, nullptr, W2T, b2, Ys16, ebase,
            1024, 1024, 1024, 256, 262144, 256);
        moe_combine_ln_kernel<<<2048, 256, 0, stream>>>(
            Ys16, X1, pos_of_tok, exp_of_tok, gate_of_tok, ebase, g2, be2, oln, oln16);
    }

    aux_kernel<<<1, 64, 0, stream>>>(counts, dout + 2 * NTOK);
}

// Round 9
// 545.019 us; speedup vs baseline: 1.3563x; 1.3563x over previous
//
#include <hip/hip_runtime.h>
#include <hip/hip_bf16.h>

typedef _Float16 f16_t;
typedef _Float16 f16x4v __attribute__((ext_vector_type(4)));
typedef _Float16 f16x8 __attribute__((ext_vector_type(8)));
typedef float f32x4 __attribute__((ext_vector_type(4)));

// ================= 128x128 GEMM core: C = A[M,K] @ B^T (B stored [N][K]) =================
// 4 waves in 2x2, each wave 64x64 via 4x4 frags of 16x16x32.
template<bool BIAS, bool RELU, bool OUTF16, bool GATHER>
__device__ __forceinline__ void gemm128_body(
    const f16_t* __restrict__ A, const f16_t* __restrict__ B,
    void* __restrict__ Cv, const float* __restrict__ bias,
    const int* __restrict__ tok_of_slot,
    int m0, int n0, int K, int lda, int ldb, int ldc)
{
    __shared__ f16_t As[128][72];
    __shared__ f16_t Bs[128][72];
    const int t = threadIdx.x, wave = t >> 6, lane = t & 63;
    const int wr2 = (wave >> 1) * 64, wc2 = (wave & 1) * 64;
    const int lr = lane & 15, kg = lane >> 4;
    const int sr = t >> 1, sc0 = (t & 1) * 32;

    const f16_t* arp;
    if constexpr (GATHER) arp = A + (long long)(tok_of_slot[m0 + sr] & 8191) * lda;
    else                  arp = A + (long long)(m0 + sr) * lda;
    const f16_t* brp = B + (long long)(n0 + sr) * ldb;

    f32x4 acc[4][4] = {};
    for (int k0 = 0; k0 < K; k0 += 64) {
        #pragma unroll
        for (int j = 0; j < 4; j++) {
            *reinterpret_cast<f16x8*>(&As[sr][sc0 + j * 8]) =
                *reinterpret_cast<const f16x8*>(&arp[k0 + sc0 + j * 8]);
            *reinterpret_cast<f16x8*>(&Bs[sr][sc0 + j * 8]) =
                *reinterpret_cast<const f16x8*>(&brp[k0 + sc0 + j * 8]);
        }
        __syncthreads();
        #pragma unroll
        for (int c = 0; c < 2; c++) {
            f16x8 av[4], bv[4];
            #pragma unroll
            for (int i = 0; i < 4; i++) {
                av[i] = *reinterpret_cast<const f16x8*>(&As[wr2 + i * 16 + lr][c * 32 + kg * 8]);
                bv[i] = *reinterpret_cast<const f16x8*>(&Bs[wc2 + i * 16 + lr][c * 32 + kg * 8]);
            }
            #pragma unroll
            for (int mi = 0; mi < 4; mi++)
                #pragma unroll
                for (int ni = 0; ni < 4; ni++)
                    acc[mi][ni] = __builtin_amdgcn_mfma_f32_16x16x32_f16(av[mi], bv[ni], acc[mi][ni], 0, 0, 0);
        }
        __syncthreads();
    }
    #pragma unroll
    for (int mi = 0; mi < 4; mi++)
        #pragma unroll
        for (int ni = 0; ni < 4; ni++)
            #pragma unroll
            for (int r = 0; r < 4; r++) {
                const int row = m0 + wr2 + mi * 16 + kg * 4 + r;
                const int col = n0 + wc2 + ni * 16 + lr;
                float v = acc[mi][ni][r];
                if constexpr (BIAS) v += bias[col];
                if constexpr (RELU) v = fmaxf(v, 0.f);
                if constexpr (OUTF16) ((f16_t*)Cv)[(long long)row * ldc + col] = (f16_t)v;
                else                  ((float*)Cv)[(long long)row * ldc + col] = v;
            }
}

template<bool BIAS, bool OUTF16>
__global__ __launch_bounds__(256) void gemm128_kernel(
    const f16_t* __restrict__ A, const f16_t* __restrict__ B, void* __restrict__ Cv,
    const float* __restrict__ bias, int K, int lda, int ldb, int ldc)
{
    gemm128_body<BIAS, false, OUTF16, false>(A, B, Cv, bias, nullptr,
                                             blockIdx.y * 128, blockIdx.x * 128, K, lda, ldb, ldc);
}

// fused Q/K/V projection: z picks {A, W, bias, out}
__global__ __launch_bounds__(256) void qkv128_kernel(
    const f16_t* __restrict__ Aq, const f16_t* __restrict__ Akv,
    const f16_t* __restrict__ B0, const f16_t* __restrict__ B1, const f16_t* __restrict__ B2,
    const float* __restrict__ bi0, const float* __restrict__ bi1, const float* __restrict__ bi2,
    f16_t* __restrict__ C0, f16_t* __restrict__ C1, f16_t* __restrict__ C2)
{
    const int zz = blockIdx.z;
    const f16_t* A = (zz == 0) ? Aq : Akv;
    const f16_t* B = (zz == 0) ? B0 : (zz == 1 ? B1 : B2);
    const float* bias = (zz == 0) ? bi0 : (zz == 1 ? bi1 : bi2);
    f16_t* C = (zz == 0) ? C0 : (zz == 1 ? C1 : C2);
    gemm128_body<true, false, true, false>(A, B, C, bias, nullptr,
                                           blockIdx.y * 128, blockIdx.x * 128, 256, 256, 256, 256);
}

// MoE GEMM: expert from 128-aligned block row
template<bool RELU, bool OUTF16, bool GATHER>
__global__ __launch_bounds__(256) void moe_gemm128_kernel(
    const f16_t* __restrict__ A, const int* __restrict__ tok_of_slot,
    const f16_t* __restrict__ W, const float* __restrict__ bias,
    void* __restrict__ Cv, const int* __restrict__ ebase,
    int K, int lda, int ldb, int ldc, int wstride, int bstride)
{
    const int m0 = blockIdx.y * 128;
    if (m0 >= ebase[8]) return;
    int e = 0;
    #pragma unroll
    for (int i = 1; i < 8; i++) if (m0 >= ebase[i]) e = i;
    gemm128_body<true, RELU, OUTF16, GATHER>(
        A, W + (long long)e * wstride, Cv, bias + e * bstride, tok_of_slot,
        m0, blockIdx.x * 128, K, lda, ldb, ldc);
}

// ================= V transpose: VT[z][d][s] from V16 [token][256] =================
__global__ __launch_bounds__(256) void vtrans_kernel(
    const f16_t* __restrict__ V16, f16_t* __restrict__ VT)
{
    __shared__ f16_t tile[32][33];
    const int z = blockIdx.z;
    const int s0 = blockIdx.x * 32, d0 = blockIdx.y * 32;
    const int tx = threadIdx.x & 31, ty = threadIdx.x >> 5;
    #pragma unroll
    for (int i = 0; i < 32; i += 8)
        tile[ty + i][tx] = V16[(long long)(s0 + ty + i) * 1024 + 64 * z + d0 + tx];
    __syncthreads();
    #pragma unroll
    for (int i = 0; i < 32; i += 8)
        VT[(long long)z * 131072 + (long long)(d0 + ty + i) * 2048 + s0 + tx] = tile[tx][ty + i];
}

// ================= flash attention, split-KV (R5 structure: Ks+VTs staged, 2 barriers) ==
// chunk c covers k in [c*512, (c+1)*512). Writes unnormalized Opart (f16) + per-row m,l.
__global__ __launch_bounds__(256) void flash_kernel(
    const f16_t* __restrict__ Q16, const f16_t* __restrict__ K16,
    const f16_t* __restrict__ VT, f16_t* __restrict__ Opart,
    float* __restrict__ mlm, float* __restrict__ mll)
{
    __shared__ f16_t Ks[64][72];
    __shared__ f16_t VTs[64][72];
    __shared__ f16_t Ps[4][16][72];

    const int z = blockIdx.y;
    const int c = blockIdx.z;
    const int m0 = blockIdx.x * 64;
    const int t = threadIdx.x, w = t >> 6, lane = t & 63;
    const int lr = lane & 15, kg = lane >> 4;
    const long long cbase = 64LL * z;

    // Q fragments, pre-scaled by 1/8 (exact pow2)
    f16x8 qf0, qf1;
    {
        const long long qrow = (long long)(m0 + w * 16 + lr) * 1024 + cbase;
        qf0 = *reinterpret_cast<const f16x8*>(&Q16[qrow + kg * 8]);
        qf1 = *reinterpret_cast<const f16x8*>(&Q16[qrow + 32 + kg * 8]);
        #pragma unroll
        for (int i = 0; i < 8; i++) { qf0[i] *= (f16_t)0.125f; qf1[i] *= (f16_t)0.125f; }
    }

    f32x4 oacc[4] = {};
    float mrun[4] = { -1e30f, -1e30f, -1e30f, -1e30f };
    float lrun[4] = {};

    const int sr = t >> 2, sc = (t & 3) * 16;
    const int nbeg = c * 512;
    for (int n0 = nbeg; n0 < nbeg + 512; n0 += 64) {
        // ---- stage K (rows=s) and VT (rows=d), pure vector copies ----
        const long long krow = (long long)(n0 + sr) * 1024 + cbase;
        const long long vrow = (long long)z * 131072 + (long long)sr * 2048 + n0;
        *reinterpret_cast<f16x8*>(&Ks[sr][sc])      = *reinterpret_cast<const f16x8*>(&K16[krow + sc]);
        *reinterpret_cast<f16x8*>(&Ks[sr][sc + 8])  = *reinterpret_cast<const f16x8*>(&K16[krow + sc + 8]);
        *reinterpret_cast<f16x8*>(&VTs[sr][sc])     = *reinterpret_cast<const f16x8*>(&VT[vrow + sc]);
        *reinterpret_cast<f16x8*>(&VTs[sr][sc + 8]) = *reinterpret_cast<const f16x8*>(&VT[vrow + sc + 8]);
        __syncthreads();

        // ---- S = (Q/8) K^T ----
        float sv[4][4];
        #pragma unroll
        for (int nt = 0; nt < 4; nt++) {
            f32x4 acc = {};
            f16x8 b0 = *reinterpret_cast<const f16x8*>(&Ks[nt * 16 + lr][kg * 8]);
            f16x8 b1 = *reinterpret_cast<const f16x8*>(&Ks[nt * 16 + lr][32 + kg * 8]);
            acc = __builtin_amdgcn_mfma_f32_16x16x32_f16(qf0, b0, acc, 0, 0, 0);
            acc = __builtin_amdgcn_mfma_f32_16x16x32_f16(qf1, b1, acc, 0, 0, 0);
            #pragma unroll
            for (int r = 0; r < 4; r++) sv[nt][r] = acc[r];
        }

        // ---- online softmax (row = kg*4+r; reduce across 16-lane group) ----
        float mnew[4], alpha[4];
        #pragma unroll
        for (int r = 0; r < 4; r++) {
            float rm = fmaxf(fmaxf(sv[0][r], sv[1][r]), fmaxf(sv[2][r], sv[3][r]));
            rm = fmaxf(rm, __shfl_xor(rm, 1));
            rm = fmaxf(rm, __shfl_xor(rm, 2));
            rm = fmaxf(rm, __shfl_xor(rm, 4));
            rm = fmaxf(rm, __shfl_xor(rm, 8));
            mnew[r] = fmaxf(mrun[r], rm);
            alpha[r] = __expf(mrun[r] - mnew[r]);
            mrun[r] = mnew[r];
        }
        #pragma unroll
        for (int nt = 0; nt < 4; nt++)
            #pragma unroll
            for (int r = 0; r < 4; r++) sv[nt][r] = __expf(sv[nt][r] - mnew[r]);
        #pragma unroll
        for (int r = 0; r < 4; r++) {
            float rs = sv[0][r] + sv[1][r] + sv[2][r] + sv[3][r];
            rs += __shfl_xor(rs, 1);
            rs += __shfl_xor(rs, 2);
            rs += __shfl_xor(rs, 4);
            rs += __shfl_xor(rs, 8);
            lrun[r] = lrun[r] * alpha[r] + rs;
        }
        #pragma unroll
        for (int dt = 0; dt < 4; dt++)
            #pragma unroll
            for (int r = 0; r < 4; r++) oacc[dt][r] *= alpha[r];

        // ---- P: C-layout -> A-layout via per-wave LDS (same-wave, no barrier) ----
        #pragma unroll
        for (int nt = 0; nt < 4; nt++)
            #pragma unroll
            for (int r = 0; r < 4; r++)
                Ps[w][kg * 4 + r][nt * 16 + lr] = (f16_t)sv[nt][r];

        f16x8 pa0 = *reinterpret_cast<const f16x8*>(&Ps[w][lr][kg * 8]);
        f16x8 pa1 = *reinterpret_cast<const f16x8*>(&Ps[w][lr][32 + kg * 8]);
        #pragma unroll
        for (int dt = 0; dt < 4; dt++) {
            f16x8 vb0 = *reinterpret_cast<const f16x8*>(&VTs[dt * 16 + lr][kg * 8]);
            f16x8 vb1 = *reinterpret_cast<const f16x8*>(&VTs[dt * 16 + lr][32 + kg * 8]);
            oacc[dt] = __builtin_amdgcn_mfma_f32_16x16x32_f16(pa0, vb0, oacc[dt], 0, 0, 0);
            oacc[dt] = __builtin_amdgcn_mfma_f32_16x16x32_f16(pa1, vb1, oacc[dt], 0, 0, 0);
        }
        __syncthreads();
    }

    // ---- write unnormalized partials (f16) + (m,l) ----
    f16_t* op = Opart + (long long)c * 2097152;
    const long long orow0 = (long long)(m0 + w * 16) * 1024 + cbase;
    #pragma unroll
    for (int r = 0; r < 4; r++)
        #pragma unroll
        for (int dt = 0; dt < 4; dt++)
            op[orow0 + (long long)(kg * 4 + r) * 1024 + dt * 16 + lr] = (f16_t)oacc[dt][r];
    if (lr == 0) {
        const int b = z >> 2, h = z & 3;
        #pragma unroll
        for (int r = 0; r < 4; r++) {
            const int tok = (m0 + w * 16 + kg * 4 + r) * 4 + b;
            const long long idx = (long long)(c * 4 + h) * 8192 + tok;
            mlm[idx] = mrun[r];
            mll[idx] = lrun[r];
        }
    }
}

// ================= merge 4 split-KV chunks -> O16 f16 =================
__global__ __launch_bounds__(256) void merge_kernel(
    const f16_t* __restrict__ Opart, const float* __restrict__ mlm,
    const float* __restrict__ mll, f16_t* __restrict__ O16)
{
    const int w = threadIdx.x >> 6, lane = threadIdx.x & 63;
    const int trow = blockIdx.x * 4 + w;
    const int h = lane >> 4;
    float m[4], l[4];
    #pragma unroll
    for (int c = 0; c < 4; c++) {
        m[c] = mlm[(long long)(c * 4 + h) * 8192 + trow];
        l[c] = mll[(long long)(c * 4 + h) * 8192 + trow];
    }
    float M = fmaxf(fmaxf(m[0], m[1]), fmaxf(m[2], m[3]));
    float wv[4], L = 0.f;
    #pragma unroll
    for (int c = 0; c < 4; c++) { wv[c] = __expf(m[c] - M); L += wv[c] * l[c]; }
    const float inv = 1.f / L;
    const long long base = (long long)trow * 256 + lane * 4;
    float acc[4] = {};
    #pragma unroll
    for (int c = 0; c < 4; c++) {
        f16x4v v = *reinterpret_cast<const f16x4v*>(&Opart[(long long)c * 2097152 + base]);
        #pragma unroll
        for (int j = 0; j < 4; j++) acc[j] += wv[c] * (float)v[j];
    }
    f16_t o[4] = { (f16_t)(acc[0] * inv), (f16_t)(acc[1] * inv),
                   (f16_t)(acc[2] * inv), (f16_t)(acc[3] * inv) };
    *reinterpret_cast<ulong1*>(&O16[base]) = *reinterpret_cast<ulong1*>(o);
}

// ================= prep kernels =================
__global__ __launch_bounds__(256) void wtrans_kernel(
    const float* __restrict__ in, f16_t* __restrict__ out, int R, int C)
{
    __shared__ float tile[32][33];
    const long long zoff = (long long)blockIdx.z * R * C;
    const int r0 = blockIdx.y * 32, c0 = blockIdx.x * 32;
    const int tx = threadIdx.x & 31, ty = threadIdx.x >> 5;
    #pragma unroll
    for (int i = 0; i < 32; i += 8)
        tile[ty + i][tx] = in[zoff + (long long)(r0 + ty + i) * C + c0 + tx];
    __syncthreads();
    #pragma unroll
    for (int i = 0; i < 32; i += 8)
        out[zoff + (long long)(c0 + ty + i) * R + r0 + tx] = (f16_t)tile[tx][ty + i];
}

__global__ __launch_bounds__(256) void wtrans4_kernel(
    const float* __restrict__ W0, const float* __restrict__ W1,
    const float* __restrict__ W2, const float* __restrict__ W3,
    f16_t* __restrict__ T0, f16_t* __restrict__ T1,
    f16_t* __restrict__ T2, f16_t* __restrict__ T3)
{
    __shared__ float tile[32][33];
    const int z = blockIdx.z;
    const float* in = (z == 0) ? W0 : (z == 1 ? W1 : (z == 2 ? W2 : W3));
    f16_t* out = (z == 0) ? T0 : (z == 1 ? T1 : (z == 2 ? T2 : T3));
    const int r0 = blockIdx.y * 32, c0 = blockIdx.x * 32;
    const int tx = threadIdx.x & 31, ty = threadIdx.x >> 5;
    #pragma unroll
    for (int i = 0; i < 32; i += 8)
        tile[ty + i][tx] = in[(long long)(r0 + ty + i) * 256 + c0 + tx];
    __syncthreads();
    #pragma unroll
    for (int i = 0; i < 32; i += 8)
        out[(long long)(c0 + ty + i) * 256 + r0 + tx] = (f16_t)tile[tx][ty + i];
}

__global__ __launch_bounds__(256) void cvt16_kernel(
    const float* __restrict__ a, const float* __restrict__ b,
    f16_t* __restrict__ oa, f16_t* __restrict__ ob)
{
    long long i = ((long long)blockIdx.x * 256 + threadIdx.x) * 4;
    const float* in = a; f16_t* out = oa;
    if (i >= 2097152) { in = b; out = ob; i -= 2097152; }
    float4 v = *reinterpret_cast<const float4*>(&in[i]);
    f16_t o[4] = { (f16_t)v.x, (f16_t)v.y, (f16_t)v.z, (f16_t)v.w };
    *reinterpret_cast<ulong1*>(&out[i]) = *reinterpret_cast<ulong1*>(o);
}

// ================= LN(in1+in2)*g+b -> f32 (+optional f16) =================
__global__ __launch_bounds__(256) void ln_kernel(
    const float* __restrict__ in1, const float* __restrict__ in2,
    const float* __restrict__ gamma, const float* __restrict__ beta,
    float* __restrict__ out, f16_t* __restrict__ out16)
{
    const int wave = threadIdx.x >> 6, lane = threadIdx.x & 63;
    const long long row = (long long)blockIdx.x * 4 + wave;
    const long long base = row * 256 + lane * 4;
    float4 a = *reinterpret_cast<const float4*>(&in1[base]);
    float4 b = *reinterpret_cast<const float4*>(&in2[base]);
    float x[4] = { a.x + b.x, a.y + b.y, a.z + b.z, a.w + b.w };
    float s = x[0] + x[1] + x[2] + x[3];
    float s2 = x[0]*x[0] + x[1]*x[1] + x[2]*x[2] + x[3]*x[3];
    #pragma unroll
    for (int o = 32; o; o >>= 1) { s += __shfl_xor(s, o); s2 += __shfl_xor(s2, o); }
    const float mean = s * (1.f / 256.f);
    const float var = s2 * (1.f / 256.f) - mean * mean;
    const float rstd = rsqrtf(var + 1e-5f);
    float4 g = *reinterpret_cast<const float4*>(&gamma[lane * 4]);
    float4 bb = *reinterpret_cast<const float4*>(&beta[lane * 4]);
    const float* gf = reinterpret_cast<const float*>(&g);
    const float* bf = reinterpret_cast<const float*>(&bb);
    float y[4];
    #pragma unroll
    for (int i = 0; i < 4; i++) y[i] = (x[i] - mean) * rstd * gf[i] + bf[i];
    *reinterpret_cast<float4*>(&out[base]) = make_float4(y[0], y[1], y[2], y[3]);
    if (out16) {
        f16_t o[4] = { (f16_t)y[0], (f16_t)y[1], (f16_t)y[2], (f16_t)y[3] };
        *reinterpret_cast<ulong1*>(&out16[base]) = *reinterpret_cast<ulong1*>(o);
    }
}

// ================= gating (1 thread/token, hierarchical) =================
__global__ __launch_bounds__(256) void gating_kernel(
    const float* __restrict__ X, const float* __restrict__ Wg, const float* __restrict__ bg,
    int* __restrict__ gcount, float* __restrict__ counts,
    int* __restrict__ pos_of_tok, int* __restrict__ exp_of_tok,
    float* __restrict__ gate_of_tok)
{
    __shared__ float WgL[2048];
    __shared__ float cpart[8];
    __shared__ int lcnt[8];
    __shared__ int lbase[8];
    const int t = threadIdx.x;
    for (int i = t; i < 2048; i += 256) WgL[i] = Wg[i];
    if (t < 8) { cpart[t] = 0.f; lcnt[t] = 0; }
    __syncthreads();

    const int tok = blockIdx.x * 256 + t;
    const float* xr = X + (long long)tok * 256;
    float acc[8] = {};
    for (int k = 0; k < 256; k += 4) {
        float4 xv = *reinterpret_cast<const float4*>(xr + k);
        const float* xf = reinterpret_cast<const float*>(&xv);
        #pragma unroll
        for (int i = 0; i < 4; i++) {
            const float xi = xf[i];
            const float* wrow = &WgL[(k + i) * 8];
            #pragma unroll
            for (int e = 0; e < 8; e++) acc[e] += xi * wrow[e];
        }
    }
    float p[8]; float mx = -1e30f;
    #pragma unroll
    for (int e = 0; e < 8; e++) { p[e] = acc[e] + bg[e]; mx = fmaxf(mx, p[e]); }
    float se = 0.f;
    #pragma unroll
    for (int e = 0; e < 8; e++) { p[e] = __expf(p[e] - mx); se += p[e]; }
    const float inv = 1.f / se;
    #pragma unroll
    for (int e = 0; e < 8; e++) { p[e] *= inv; atomicAdd(&cpart[e], p[e]); }

    int i1 = 0;
    #pragma unroll
    for (int e = 1; e < 8; e++) if (p[e] > p[i1]) i1 = e;
    int i2 = (i1 == 0) ? 1 : 0;
    #pragma unroll
    for (int e = 0; e < 8; e++) if (e != i1 && p[e] > p[i2]) i2 = e;
    const float gs = 1.f / (p[i1] + p[i2]);

    const int p1 = atomicAdd(&lcnt[i1], 1);
    const int p2 = atomicAdd(&lcnt[i2], 1);
    __syncthreads();
    if (t < 8) {
        lbase[t] = atomicAdd(&gcount[t], lcnt[t]);
        atomicAdd(&counts[t], cpart[t]);
    }
    __syncthreads();
    pos_of_tok[2 * tok]     = lbase[i1] + p1;
    pos_of_tok[2 * tok + 1] = lbase[i2] + p2;
    exp_of_tok[2 * tok]     = i1;
    exp_of_tok[2 * tok + 1] = i2;
    gate_of_tok[2 * tok]     = p[i1] * gs;
    gate_of_tok[2 * tok + 1] = p[i2] * gs;
}

// 128-aligned prefix bases (tiles never span experts)
__global__ void finalize_kernel(const int* __restrict__ gcount, int* __restrict__ ebase)
{
    if (threadIdx.x == 0) {
        int b = 0;
        for (int e = 0; e < 8; e++) { ebase[e] = b; b += (gcount[e] + 127) & ~127; }
        ebase[8] = b;
    }
}

__global__ __launch_bounds__(256) void scatter_kernel(
    const int* __restrict__ pos_of_tok, const int* __restrict__ exp_of_tok,
    const int* __restrict__ ebase, int* __restrict__ tok_of_slot)
{
    const int i = blockIdx.x * 256 + threadIdx.x;
    const int e = exp_of_tok[i];
    tok_of_slot[ebase[e] + pos_of_tok[i]] = i >> 1;
}

// out = LN(gv1*Ys[s1] + gv2*Ys[s2] + X1), Ys f16
__global__ __launch_bounds__(256) void moe_combine_ln_kernel(
    const f16_t* __restrict__ Ys, const float* __restrict__ X1,
    const int* __restrict__ pos_of_tok, const int* __restrict__ exp_of_tok,
    const float* __restrict__ gate_of_tok, const int* __restrict__ ebase,
    const float* __restrict__ gamma, const float* __restrict__ beta,
    float* __restrict__ out, f16_t* __restrict__ out16)
{
    const int wave = threadIdx.x >> 6, lane = threadIdx.x & 63;
    const long long tok = (long long)blockIdx.x * 4 + wave;
    const int e1 = exp_of_tok[2 * tok], e2 = exp_of_tok[2 * tok + 1];
    const long long s1 = ebase[e1] + pos_of_tok[2 * tok];
    const long long s2 = ebase[e2] + pos_of_tok[2 * tok + 1];
    const float gv1 = gate_of_tok[2 * tok], gv2 = gate_of_tok[2 * tok + 1];
    const long long base = tok * 256 + lane * 4;
    f16x4v y1 = *reinterpret_cast<const f16x4v*>(&Ys[s1 * 256 + lane * 4]);
    f16x4v y2 = *reinterpret_cast<const f16x4v*>(&Ys[s2 * 256 + lane * 4]);
    float4 xv = *reinterpret_cast<const float4*>(&X1[base]);
    const float* xf = reinterpret_cast<const float*>(&xv);
    float x[4];
    #pragma unroll
    for (int i = 0; i < 4; i++) x[i] = gv1 * (float)y1[i] + gv2 * (float)y2[i] + xf[i];
    float s = x[0] + x[1] + x[2] + x[3];
    float s2v = x[0]*x[0] + x[1]*x[1] + x[2]*x[2] + x[3]*x[3];
    #pragma unroll
    for (int o = 32; o; o >>= 1) { s += __shfl_xor(s, o); s2v += __shfl_xor(s2v, o); }
    const float mean = s * (1.f / 256.f);
    const float var = s2v * (1.f / 256.f) - mean * mean;
    const float rstd = rsqrtf(var + 1e-5f);
    float4 g = *reinterpret_cast<const float4*>(&gamma[lane * 4]);
    float4 bb = *reinterpret_cast<const float4*>(&beta[lane * 4]);
    const float* gf = reinterpret_cast<const float*>(&g);
    const float* bf = reinterpret_cast<const float*>(&bb);
    float y[4];
    #pragma unroll
    for (int i = 0; i < 4; i++) y[i] = (x[i] - mean) * rstd * gf[i] + bf[i];
    *reinterpret_cast<float4*>(&out[base]) = make_float4(y[0], y[1], y[2], y[3]);
    if (out16) {
        f16_t o[4] = { (f16_t)y[0], (f16_t)y[1], (f16_t)y[2], (f16_t)y[3] };
        *reinterpret_cast<ulong1*>(&out16[base]) = *reinterpret_cast<ulong1*>(o);
    }
}

__global__ void aux_kernel(const float* __restrict__ counts, float* __restrict__ out)
{
    if (threadIdx.x == 0) {
        float aux = 0.f;
        for (int pzz = 0; pzz < 2; pzz++) {
            const float* c = counts + pzz * 8;
            float tot = 0.f;
            for (int e = 0; e < 8; e++) tot += c[e];
            float s = 0.f;
            for (int e = 0; e < 8; e++) s += (c[e] / tot) * (c[e] * (1.f / 8192.f));
            aux += 8.f * s;
        }
        out[0] = 0.01f * aux;
    }
}

extern "C" void kernel_launch(void* const* d_in, const int* in_sizes, int n_in,
                              void* d_out, int out_size, void* d_ws, size_t ws_size,
                              hipStream_t stream)
{
    const float* Xc  = (const float*)d_in[0];
    const float* Xt  = (const float*)d_in[1];
    const float* Wq  = (const float*)d_in[2];
    const float* Wk  = (const float*)d_in[3];
    const float* Wv  = (const float*)d_in[4];
    const float* bq  = (const float*)d_in[5];
    const float* bk  = (const float*)d_in[6];
    const float* bv  = (const float*)d_in[7];
    const float* Wo  = (const float*)d_in[8];
    const float* bo  = (const float*)d_in[9];
    const float* Wg  = (const float*)d_in[10];
    const float* bg  = (const float*)d_in[11];
    const float* W1  = (const float*)d_in[12];
    const float* b1  = (const float*)d_in[13];
    const float* W2  = (const float*)d_in[14];
    const float* b2  = (const float*)d_in[15];
    const float* g_c1 = (const float*)d_in[16];
    const float* b_c1 = (const float*)d_in[17];
    const float* g_c2 = (const float*)d_in[18];
    const float* b_c2 = (const float*)d_in[19];
    const float* g_t1 = (const float*)d_in[20];
    const float* b_t1 = (const float*)d_in[21];
    const float* g_t2 = (const float*)d_in[22];
    const float* b_t2 = (const float*)d_in[23];

    const long long NTOK = 2097152;          // 8192 tokens * 256
    const int SLOT_MAX = 17408;              // 136 * 128 (128-aligned expert bases)
    float* dout = (float*)d_out;             // fp32: xc | xt | aux
    float* xcout = dout;
    float* xtout = dout + NTOK;

    float* ws = (float*)d_ws;
    float* P1 = ws;
    float* X1 = P1 + NTOK;
    float* counts      = X1 + NTOK;                      // 16 f32
    int*   gcount      = (int*)(counts + 16);            // 16 i32 (adjacent: one memset)
    float* gate_of_tok = (float*)(gcount + 16);          // 16384
    float* mlm = gate_of_tok + 16384;                    // 4*4*8192
    float* mll = mlm + 131072;                           // 4*4*8192
    int* ebase       = (int*)(mll + 131072);             // 16
    int* pos_of_tok  = ebase + 16;                       // 16384
    int* exp_of_tok  = pos_of_tok + 16384;               // 16384
    int* tok_of_slot = exp_of_tok + 16384;               // SLOT_MAX
    f16_t* h16 = (f16_t*)(tok_of_slot + SLOT_MAX);
    f16_t* Xc16 = h16;
    f16_t* Xt16 = Xc16 + NTOK;
    f16_t* xc16 = Xt16 + NTOK;
    f16_t* Q16  = xc16 + NTOK;
    f16_t* K16  = Q16 + NTOK;
    f16_t* V16  = K16 + NTOK;
    f16_t* O16  = V16 + NTOK;
    f16_t* X116 = O16 + NTOK;
    f16_t* VT   = X116 + NTOK;                           // 16 z x 64 d x 2048 s
    f16_t* Hs16 = VT + NTOK;                             // SLOT_MAX x 1024 (MoE phase)
    f16_t* Ys16 = Hs16 + (long long)SLOT_MAX * 1024;     // SLOT_MAX x 256
    f16_t* WqT  = Ys16 + (long long)SLOT_MAX * 256;
    f16_t* WkT  = WqT + 65536;
    f16_t* WvT  = WkT + 65536;
    f16_t* WoT  = WvT + 65536;
    f16_t* W1T  = WoT + 65536;                           // 8 x 1024 x 256
    f16_t* W2T  = W1T + 2097152;                         // 8 x 256 x 1024
    f16_t* Opart = Hs16;                                 // alias: attention phase only (4*NTOK f16 = 16MB)

    hipMemsetAsync(counts, 0, 32 * sizeof(int), stream);   // counts(16f) + gcount(16i)

    // ---- prep ----
    cvt16_kernel<<<4096, 256, 0, stream>>>(Xc, Xt, Xc16, Xt16);
    wtrans4_kernel<<<dim3(8, 8, 4), 256, 0, stream>>>(Wq, Wk, Wv, Wo, WqT, WkT, WvT, WoT);
    wtrans_kernel<<<dim3(32, 8, 8), 256, 0, stream>>>(W1, W1T, 256, 1024);
    wtrans_kernel<<<dim3(8, 32, 8), 256, 0, stream>>>(W2, W2T, 1024, 256);

    for (int pass = 0; pass < 2; pass++) {
        const float*  xq    = pass ? Xt   : Xc;
        const f16_t*  xq16  = pass ? Xt16 : Xc16;
        const f16_t*  xkv16 = pass ? xc16 : Xc16;
        const float* g1  = pass ? g_t1 : g_c1;
        const float* be1 = pass ? b_t1 : b_c1;
        const float* g2  = pass ? g_t2 : g_c2;
        const float* be2 = pass ? b_t2 : b_c2;
        float* cnt = counts + pass * 8;
        int* gcnt  = gcount + pass * 8;
        float* oln = pass ? xtout : xcout;
        f16_t* oln16 = pass ? nullptr : xc16;

        // Q/K/V projections in one dispatch (128^2 tiles)
        qkv128_kernel<<<dim3(2, 64, 3), 256, 0, stream>>>(
            xq16, xkv16, WqT, WkT, WvT, bq, bk, bv, Q16, K16, V16);

        // V -> VT[z][d][s], then split-KV flash + merge
        vtrans_kernel<<<dim3(64, 2, 16), 256, 0, stream>>>(V16, VT);
        flash_kernel<<<dim3(32, 16, 4), 256, 0, stream>>>(Q16, K16, VT, Opart, mlm, mll);
        merge_kernel<<<2048, 256, 0, stream>>>(Opart, mlm, mll, O16);

        // output projection + LN1 (dual f32/f16)
        gemm128_kernel<true, false><<<dim3(2, 64), 256, 0, stream>>>(
            O16, WoT, P1, bo, 256, 256, 256, 256);
        ln_kernel<<<2048, 256, 0, stream>>>(P1, xq, g1, be1, X1, X116);

        // ---- sparse top-2 MoE ----
        gating_kernel<<<32, 256, 0, stream>>>(X1, Wg, bg, gcnt, cnt,
                                              pos_of_tok, exp_of_tok, gate_of_tok);
        finalize_kernel<<<1, 64, 0, stream>>>(gcnt, ebase);
        scatter_kernel<<<64, 256, 0, stream>>>(pos_of_tok, exp_of_tok, ebase, tok_of_slot);
        moe_gemm128_kernel<true, true, true><<<dim3(8, 136), 256, 0, stream>>>(
            X116, tok_of_slot, W1T, b1, Hs16, ebase,
            256, 256, 256, 1024, 262144, 1024);
        moe_gemm128_kernel<false, true, false><<<dim3(2, 136), 256, 0, stream>>>(
            Hs16, nullptr, W2T, b2, Ys16, ebase,
            1024, 1024, 1024, 256, 262144, 256);
        moe_combine_ln_kernel<<<2048, 256, 0, stream>>>(
            Ys16, X1, pos_of_tok, exp_of_tok, gate_of_tok, ebase, g2, be2, oln, oln16);
    }

    aux_kernel<<<1, 64, 0, stream>>>(counts, dout + 2 * NTOK);
}